// Round 3
// baseline (2423.189 us; speedup 1.0000x reference)
//
#include <hip/hip_runtime.h>

#define D 64
#define SCAN_B 1024

__device__ __forceinline__ float sigmoidf_(float x) {
    return 1.0f / (1.0f + __expf(-x));
}
__device__ __forceinline__ float h2f(ushort u) {
    _Float16 h;
    __builtin_memcpy(&h, &u, 2);
    return (float)h;
}
__device__ __forceinline__ ushort f2h(float f) {
    _Float16 h = (_Float16)f;  // v_cvt_f16_f32, RNE
    ushort u;
    __builtin_memcpy(&u, &h, 2);
    return u;
}

// ---------------- precompute kernels ----------------

__global__ __launch_bounds__(256) void count_deg(const int* __restrict__ dst,
                                                 int* __restrict__ cnt, int E) {
    int e = blockIdx.x * 256 + threadIdx.x;
    if (e < E) atomicAdd(&cnt[dst[e]], 1);
}

__global__ __launch_bounds__(256) void calc_dinv(const int* __restrict__ cnt,
                                                 float* __restrict__ dinv,
                                                 float* __restrict__ rdinv, int N) {
    int n = blockIdx.x * 256 + threadIdx.x;
    if (n < N) {
        float c = (float)cnt[n] + 1.0f;
        dinv[n] = rsqrtf(c);
        rdinv[n] = sqrtf(c);
    }
}

__global__ __launch_bounds__(SCAN_B) void scan_block(const int* __restrict__ cnt,
                                                     int* __restrict__ out,
                                                     int* __restrict__ bsum, int N) {
    __shared__ int tmp[SCAN_B];
    int t = threadIdx.x;
    int gbase = blockIdx.x * SCAN_B;
    int v = (gbase + t < N) ? cnt[gbase + t] : 0;
    tmp[t] = v;
    __syncthreads();
    for (int off = 1; off < SCAN_B; off <<= 1) {
        int x = (t >= off) ? tmp[t - off] : 0;
        __syncthreads();
        tmp[t] += x;
        __syncthreads();
    }
    int incl = tmp[t];
    if (gbase + t < N) out[gbase + t] = incl - v;  // exclusive
    if (t == SCAN_B - 1) bsum[blockIdx.x] = incl;
}

__global__ __launch_bounds__(256) void scan_add(int* __restrict__ ptr,
                                                const int* __restrict__ boff,
                                                int* __restrict__ cursor, int N, int E) {
    int i = blockIdx.x * 256 + threadIdx.x;
    if (i < N) {
        int v = ptr[i] + boff[i / SCAN_B];
        ptr[i] = v;
        cursor[i] = v;
    }
    if (i == 0) ptr[N] = E;
}

__global__ __launch_bounds__(256) void fill_csr(const int* __restrict__ src,
                                                const int* __restrict__ dst,
                                                int* __restrict__ cursor,
                                                int* __restrict__ sorted, int E) {
    int e = blockIdx.x * 256 + threadIdx.x;
    if (e < E) {
        int p = atomicAdd(&cursor[dst[e]], 1);
        sorted[p] = src[e];
    }
}

// q[n] = Agg(1)[n] = dinv[n]*(sum_nbr dinv[src] + dinv[n])
__global__ __launch_bounds__(256) void qsum_k(const int* __restrict__ ptr,
                                              const int* __restrict__ srcs,
                                              const float* __restrict__ dinv,
                                              float* __restrict__ q, int N) {
    int n = blockIdx.x * 256 + threadIdx.x;
    if (n >= N) return;
    float s = dinv[n];
    int b = ptr[n], e = ptr[n + 1];
    for (int i = b; i < e; i++) s += dinv[srcs[i]];
    q[n] = dinv[n] * s;
}

// actd0 = fp16(x * dinv[n])
__global__ __launch_bounds__(256) void prep_xd(const float* __restrict__ x,
                                               const float* __restrict__ dinv,
                                               ushort* __restrict__ actd, int N16) {
    int p = blockIdx.x * 256 + threadIdx.x;
    if (p >= N16) return;
    int n = p >> 4;
    float d = dinv[n];
    float4 v = reinterpret_cast<const float4*>(x)[p];
    ushort4 o;
    o.x = f2h(v.x * d);
    o.y = f2h(v.y * d);
    o.z = f2h(v.z * d);
    o.w = f2h(v.w * d);
    reinterpret_cast<ushort4*>(actd)[p] = o;
}

// ---------------- per-layer kernels ----------------

// z[n] = dinv[n] * (actd[n] + sum_{src in N(n)} actd[src])   [actd = fp16(act*dinv)]
// optional: BN stats of act = actd*rdinv  (stats of the layer that produced actd)
__global__ __launch_bounds__(256) void agg_gather(const ushort* __restrict__ actd,
                                                  const int* __restrict__ ptr,
                                                  const int* __restrict__ srcs,
                                                  const float* __restrict__ dinv,
                                                  const float* __restrict__ rdinv,
                                                  float* __restrict__ z,
                                                  float* __restrict__ ssum,
                                                  float* __restrict__ sssq, int N) {
    __shared__ float red[2][4][64];
    int lane = threadIdx.x & 63;
    int wv = threadIdx.x >> 6;
    float psum = 0.f, pssq = 0.f;
    for (int n = blockIdx.x * 4 + wv; n < N; n += gridDim.x * 4) {
        int s = __builtin_amdgcn_readfirstlane(ptr[n]);
        int e = __builtin_amdgcn_readfirstlane(ptr[n + 1]);
        float acc = h2f(actd[(size_t)n * 64 + lane]);
        if (ssum) {
            float a = acc * rdinv[n];
            psum += a;
            pssq += a * a;
        }
        int i = s;
        for (; i + 3 < e; i += 4) {
            int u0 = srcs[i], u1 = srcs[i + 1], u2 = srcs[i + 2], u3 = srcs[i + 3];
            float v0 = h2f(actd[(size_t)u0 * 64 + lane]);
            float v1 = h2f(actd[(size_t)u1 * 64 + lane]);
            float v2 = h2f(actd[(size_t)u2 * 64 + lane]);
            float v3 = h2f(actd[(size_t)u3 * 64 + lane]);
            acc += (v0 + v1) + (v2 + v3);
        }
        for (; i < e; i++) acc += h2f(actd[(size_t)srcs[i] * 64 + lane]);
        z[(size_t)n * 64 + lane] = acc * dinv[n];
    }
    if (ssum) {
        red[0][wv][lane] = psum;
        red[1][wv][lane] = pssq;
        __syncthreads();
        if (wv == 0) {
            float t0 = red[0][0][lane] + red[0][1][lane] + red[0][2][lane] + red[0][3][lane];
            float t1 = red[1][0][lane] + red[1][1][lane] + red[1][2][lane] + red[1][3][lane];
            atomicAdd(&ssum[lane], t0);
            atomicAdd(&sssq[lane], t1);
        }
    }
}

// pre[n][j] = sum_k z[n][k]*A[k]*W[k][j] + q[n]*u[j] + b[j]; act = mode(pre)
// out_h   : actd_next = fp16(act*dinv)   (for next gather)
// out_f32 : act raw f32 (terminal layers; may alias z -> no restrict on z/out_f32)
__global__ __launch_bounds__(256) void gemm_fused(const float* z,
                                                  const float* __restrict__ W,
                                                  const float* __restrict__ Aaf,
                                                  const float* __restrict__ u,
                                                  const float* __restrict__ bias,
                                                  const float* __restrict__ q,
                                                  const float* __restrict__ dinv,
                                                  ushort* __restrict__ out_h,
                                                  float* out_f32, int mode, int N) {
    int n = blockIdx.x * 256 + threadIdx.x;
    if (n >= N) return;
    float row[64];
    const float4* z4 = reinterpret_cast<const float4*>(z) + (size_t)n * 16;
#pragma unroll
    for (int kk = 0; kk < 16; kk++) {
        float4 v = z4[kk];
        row[4 * kk + 0] = v.x;
        row[4 * kk + 1] = v.y;
        row[4 * kk + 2] = v.z;
        row[4 * kk + 3] = v.w;
    }
    if (Aaf) {
#pragma unroll
        for (int k = 0; k < 64; k++) row[k] *= Aaf[k];
    }
    float qn = (u != nullptr) ? q[n] : 0.0f;
    float dn = dinv[n];
#pragma unroll
    for (int cg = 0; cg < 4; cg++) {
        float acc[16];
#pragma unroll
        for (int j = 0; j < 16; j++) {
            float base = bias[cg * 16 + j];
            if (u) base = fmaf(qn, u[cg * 16 + j], base);
            acc[j] = base;
        }
#pragma unroll
        for (int k = 0; k < 64; k++) {
            float r = row[k];
#pragma unroll
            for (int j = 0; j < 16; j++)
                acc[j] = fmaf(r, W[k * 64 + cg * 16 + j], acc[j]);
        }
#pragma unroll
        for (int j = 0; j < 16; j++) {
            float o = acc[j];
            acc[j] = (mode == 0) ? sigmoidf_(o) : (mode == 1 ? o : sigmoidf_(0.5f * o));
        }
        if (out_h) {
            uint p[8];
#pragma unroll
            for (int jj = 0; jj < 8; jj++) {
                ushort lo = f2h(acc[2 * jj] * dn);
                ushort hi = f2h(acc[2 * jj + 1] * dn);
                p[jj] = (uint)lo | ((uint)hi << 16);
            }
            uint4* ob = reinterpret_cast<uint4*>(out_h + (size_t)n * 64 + cg * 16);
            ob[0] = make_uint4(p[0], p[1], p[2], p[3]);
            ob[1] = make_uint4(p[4], p[5], p[6], p[7]);
        } else {
            float4* of = reinterpret_cast<float4*>(out_f32 + (size_t)n * 64 + cg * 16);
            of[0] = make_float4(acc[0], acc[1], acc[2], acc[3]);
            of[1] = make_float4(acc[4], acc[5], acc[6], acc[7]);
            of[2] = make_float4(acc[8], acc[9], acc[10], acc[11]);
            of[3] = make_float4(acc[12], acc[13], acc[14], acc[15]);
        }
    }
}

__global__ __launch_bounds__(256) void stats_f32(const float* __restrict__ act,
                                                 float* __restrict__ ssum,
                                                 float* __restrict__ sssq, int N) {
    __shared__ float red[2][4][64];
    int lane = threadIdx.x & 63;
    int wv = threadIdx.x >> 6;
    float ps = 0.f, pq = 0.f;
    for (int n = blockIdx.x * 4 + wv; n < N; n += gridDim.x * 4) {
        float a = act[(size_t)n * 64 + lane];
        ps += a;
        pq += a * a;
    }
    red[0][wv][lane] = ps;
    red[1][wv][lane] = pq;
    __syncthreads();
    if (wv == 0) {
        float t0 = red[0][0][lane] + red[0][1][lane] + red[0][2][lane] + red[0][3][lane];
        float t1 = red[1][0][lane] + red[1][1][lane] + red[1][2][lane] + red[1][3][lane];
        atomicAdd(&ssum[lane], t0);
        atomicAdd(&sssq[lane], t1);
    }
}

// A[c] = rsqrt(var+eps)*gamma[c];  C[c] = beta[c] - mean*A[c]
__global__ __launch_bounds__(64) void finalize_aff(const float* __restrict__ ssum,
                                                   const float* __restrict__ sssq,
                                                   const float* __restrict__ gamma,
                                                   const float* __restrict__ beta,
                                                   float* __restrict__ A,
                                                   float* __restrict__ C, float invN) {
    int c = threadIdx.x;
    float m = ssum[c] * invN;
    float var = sssq[c] * invN - m * m;
    float rs = rsqrtf(var + 1e-4f);
    float a = rs * gamma[c];
    A[c] = a;
    C[c] = fmaf(-m, a, beta[c]);
}

// u[j] = sum_k C[k]*W[k][j]
__global__ __launch_bounds__(64) void compute_u(const float* __restrict__ C,
                                                const float* __restrict__ W,
                                                float* __restrict__ u) {
    int j = threadIdx.x;
    float s = 0.f;
    for (int k = 0; k < 64; k++) s = fmaf(C[k], W[k * 64 + j], s);
    u[j] = s;
}

__global__ __launch_bounds__(256) void bn_apply_h(const ushort* __restrict__ actd,
                                                  const float* __restrict__ rdinv,
                                                  const float* __restrict__ A,
                                                  const float* __restrict__ C,
                                                  float* __restrict__ out, int N16) {
    int p = blockIdx.x * 256 + threadIdx.x;
    if (p >= N16) return;
    int n = p >> 4;
    int cb = (p & 15) * 4;
    float r = rdinv[n];
    ushort4 v = reinterpret_cast<const ushort4*>(actd)[p];
    float4 o;
    o.x = fmaf(h2f(v.x) * r, A[cb + 0], C[cb + 0]);
    o.y = fmaf(h2f(v.y) * r, A[cb + 1], C[cb + 1]);
    o.z = fmaf(h2f(v.z) * r, A[cb + 2], C[cb + 2]);
    o.w = fmaf(h2f(v.w) * r, A[cb + 3], C[cb + 3]);
    reinterpret_cast<float4*>(out)[p] = o;
}

__global__ __launch_bounds__(256) void bn_apply_f32(const float* __restrict__ act,
                                                    const float* __restrict__ A,
                                                    const float* __restrict__ C,
                                                    float* __restrict__ out, int N16) {
    int p = blockIdx.x * 256 + threadIdx.x;
    if (p >= N16) return;
    int cb = (p & 15) * 4;
    float4 v = reinterpret_cast<const float4*>(act)[p];
    float4 o;
    o.x = fmaf(v.x, A[cb + 0], C[cb + 0]);
    o.y = fmaf(v.y, A[cb + 1], C[cb + 1]);
    o.z = fmaf(v.z, A[cb + 2], C[cb + 2]);
    o.w = fmaf(v.w, A[cb + 3], C[cb + 3]);
    reinterpret_cast<float4*>(out)[p] = o;
}

// ---------------- launch ----------------

extern "C" void kernel_launch(void* const* d_in, const int* in_sizes, int n_in,
                              void* d_out, int out_size, void* d_ws, size_t ws_size,
                              hipStream_t stream) {
    const int N = in_sizes[0] / D;
    const int E = in_sizes[1] / 2;

    const float* x = (const float*)d_in[0];
    const int* ei = (const int*)d_in[1];
    const int* src_in = ei;
    const int* dst_in = ei + E;
    const float* encW = (const float*)d_in[3];
    const float* encb = (const float*)d_in[4];
    const float* encg = (const float*)d_in[5];
    const float* encbe = (const float*)d_in[6];
    const float* attW = (const float*)d_in[7];
    const float* attb = (const float*)d_in[8];
    const float* attg = (const float*)d_in[9];
    const float* attbe = (const float*)d_in[10];
    const float* strW = (const float*)d_in[11];
    const float* strb = (const float*)d_in[12];
    const float* strg = (const float*)d_in[13];
    const float* strbe = (const float*)d_in[14];

    char* ws = (char*)d_ws;
    size_t off = 0;
    auto alloc = [&](size_t bytes) -> char* {
        char* p = ws + off;
        off += (bytes + 255) & ~(size_t)255;
        return p;
    };
    int* cnt = (int*)alloc((size_t)N * 4);
    int* csr = (int*)alloc((size_t)(N + 1) * 4);
    int* cursor = (int*)alloc((size_t)N * 4);
    int* sorted = (int*)alloc((size_t)E * 4);
    int* bsum = (int*)alloc(1024 * 4);
    int* boff = (int*)alloc(1024 * 4);
    int* dummy = (int*)alloc(1024 * 4);
    float* dinv = (float*)alloc((size_t)N * 4);
    float* rdinv = (float*)alloc((size_t)N * 4);
    float* q = (float*)alloc((size_t)N * 4);
    float* stats = (float*)alloc(6 * 128 * 4);
    float* aff = (float*)alloc(6 * 128 * 4);
    float* ubuf = (float*)alloc(6 * 64 * 4);
    float* z = (float*)alloc((size_t)N * D * 4);
    ushort* hA = (ushort*)alloc((size_t)N * D * 2);
    ushort* hB = (ushort*)alloc((size_t)N * D * 2);

    float* out_str = (float*)d_out;
    float* out_att = out_str + (size_t)N * D;
    float* out_enc = out_att + (size_t)N * D;

    hipMemsetAsync(cnt, 0, (size_t)N * 4, stream);
    hipMemsetAsync(stats, 0, 6 * 128 * 4, stream);

    int gE = (E + 255) / 256;
    int gN = (N + 255) / 256;
    int nsb = (N + SCAN_B - 1) / SCAN_B;
    int N16 = N * 16;
    int g16 = (N16 + 255) / 256;
    float invN = 1.0f / (float)N;

    // ---- CSR build + norm precompute ----
    count_deg<<<gE, 256, 0, stream>>>(dst_in, cnt, E);
    calc_dinv<<<gN, 256, 0, stream>>>(cnt, dinv, rdinv, N);
    scan_block<<<nsb, SCAN_B, 0, stream>>>(cnt, csr, bsum, N);
    scan_block<<<1, SCAN_B, 0, stream>>>(bsum, boff, dummy, nsb);
    scan_add<<<gN, 256, 0, stream>>>(csr, boff, cursor, N, E);
    fill_csr<<<gE, 256, 0, stream>>>(src_in, dst_in, cursor, sorted, E);
    qsum_k<<<gN, 256, 0, stream>>>(csr, sorted, dinv, q, N);

    float* A0 = aff + 0 * 128; float* C0 = A0 + 64;
    float* A1 = aff + 1 * 128; float* C1 = A1 + 64;
    float* A2 = aff + 2 * 128; float* C2 = A2 + 64;
    float* A3 = aff + 3 * 128; float* C3 = A3 + 64;
    float* A4 = aff + 4 * 128; float* C4 = A4 + 64;
    float* A5 = aff + 5 * 128; float* C5 = A5 + 64;

    // ---- encoder layer 1 ----
    prep_xd<<<g16, 256, 0, stream>>>(x, dinv, hA, N16);
    agg_gather<<<2048, 256, 0, stream>>>(hA, csr, sorted, dinv, rdinv, z,
                                         nullptr, nullptr, N);
    gemm_fused<<<gN, 256, 0, stream>>>(z, encW, nullptr, nullptr, encb, q, dinv,
                                       hB, nullptr, 0, N);
    // ---- encoder layer 2 ----
    agg_gather<<<2048, 256, 0, stream>>>(hB, csr, sorted, dinv, rdinv, z,
                                         stats + 0, stats + 64, N);
    finalize_aff<<<1, 64, 0, stream>>>(stats + 0, stats + 64, encg, encbe, A0, C0, invN);
    compute_u<<<1, 64, 0, stream>>>(C0, encW + 4096, ubuf + 0);
    gemm_fused<<<gN, 256, 0, stream>>>(z, encW + 4096, A0, ubuf + 0, encb + 64,
                                       q, dinv, hA, nullptr, 0, N);
    // ---- z2 = Agg(x_enc-act), shared by att1 & str1; also enc2 stats ----
    agg_gather<<<2048, 256, 0, stream>>>(hA, csr, sorted, dinv, rdinv, z,
                                         stats + 128, stats + 192, N);
    finalize_aff<<<1, 64, 0, stream>>>(stats + 128, stats + 192, encg + 64,
                                       encbe + 64, A1, C1, invN);
    compute_u<<<1, 64, 0, stream>>>(C1, attW, ubuf + 64);
    compute_u<<<1, 64, 0, stream>>>(C1, strW, ubuf + 128);
    bn_apply_h<<<g16, 256, 0, stream>>>(hA, rdinv, A1, C1, out_enc, N16);
    gemm_fused<<<gN, 256, 0, stream>>>(z, attW, A1, ubuf + 64, attb, q, dinv,
                                       hB, nullptr, 0, N);
    gemm_fused<<<gN, 256, 0, stream>>>(z, strW, A1, ubuf + 128, strb, q, dinv,
                                       hA, nullptr, 0, N);
    // ---- attribute layer 2 (terminal, linear) ----
    agg_gather<<<2048, 256, 0, stream>>>(hB, csr, sorted, dinv, rdinv, z,
                                         stats + 256, stats + 320, N);
    finalize_aff<<<1, 64, 0, stream>>>(stats + 256, stats + 320, attg, attbe,
                                       A2, C2, invN);
    compute_u<<<1, 64, 0, stream>>>(C2, attW + 4096, ubuf + 192);
    gemm_fused<<<gN, 256, 0, stream>>>(z, attW + 4096, A2, ubuf + 192, attb + 64,
                                       q, dinv, nullptr, z, 1, N);
    stats_f32<<<2048, 256, 0, stream>>>(z, stats + 384, stats + 448, N);
    finalize_aff<<<1, 64, 0, stream>>>(stats + 384, stats + 448, attg + 64,
                                       attbe + 64, A3, C3, invN);
    bn_apply_f32<<<g16, 256, 0, stream>>>(z, A3, C3, out_att, N16);
    // ---- structure layer 2 (terminal, sigmoid(0.5x)) ----
    agg_gather<<<2048, 256, 0, stream>>>(hA, csr, sorted, dinv, rdinv, z,
                                         stats + 512, stats + 576, N);
    finalize_aff<<<1, 64, 0, stream>>>(stats + 512, stats + 576, strg, strbe,
                                       A4, C4, invN);
    compute_u<<<1, 64, 0, stream>>>(C4, strW + 4096, ubuf + 320);
    gemm_fused<<<gN, 256, 0, stream>>>(z, strW + 4096, A4, ubuf + 320, strb + 64,
                                       q, dinv, nullptr, z, 2, N);
    stats_f32<<<2048, 256, 0, stream>>>(z, stats + 640, stats + 704, N);
    finalize_aff<<<1, 64, 0, stream>>>(stats + 640, stats + 704, strg + 64,
                                       strbe + 64, A5, C5, invN);
    bn_apply_f32<<<g16, 256, 0, stream>>>(z, A5, C5, out_str, N16);
}

// Round 4
// 1436.312 us; speedup vs baseline: 1.6871x; 1.6871x over previous
//
#include <hip/hip_runtime.h>

#define D 64
#define SCAN_B 1024

__device__ __forceinline__ float sigmoidf_(float x) {
    return 1.0f / (1.0f + __expf(-x));
}
__device__ __forceinline__ float h2f(ushort u) {
    _Float16 h;
    __builtin_memcpy(&h, &u, 2);
    return (float)h;
}
__device__ __forceinline__ ushort f2h(float f) {
    _Float16 h = (_Float16)f;  // v_cvt_f16_f32, RNE
    ushort u;
    __builtin_memcpy(&u, &h, 2);
    return u;
}

// ---------------- precompute kernels ----------------

__global__ __launch_bounds__(256) void count_deg(const int* __restrict__ dst,
                                                 int* __restrict__ cnt, int E) {
    int e = blockIdx.x * 256 + threadIdx.x;
    if (e < E) atomicAdd(&cnt[dst[e]], 1);
}

__global__ __launch_bounds__(256) void calc_dinv(const int* __restrict__ cnt,
                                                 float* __restrict__ dinv,
                                                 float* __restrict__ rdinv, int N) {
    int n = blockIdx.x * 256 + threadIdx.x;
    if (n < N) {
        float c = (float)cnt[n] + 1.0f;
        dinv[n] = rsqrtf(c);
        rdinv[n] = sqrtf(c);
    }
}

__global__ __launch_bounds__(SCAN_B) void scan_block(const int* __restrict__ cnt,
                                                     int* __restrict__ out,
                                                     int* __restrict__ bsum, int N) {
    __shared__ int tmp[SCAN_B];
    int t = threadIdx.x;
    int gbase = blockIdx.x * SCAN_B;
    int v = (gbase + t < N) ? cnt[gbase + t] : 0;
    tmp[t] = v;
    __syncthreads();
    for (int off = 1; off < SCAN_B; off <<= 1) {
        int x = (t >= off) ? tmp[t - off] : 0;
        __syncthreads();
        tmp[t] += x;
        __syncthreads();
    }
    int incl = tmp[t];
    if (gbase + t < N) out[gbase + t] = incl - v;  // exclusive
    if (t == SCAN_B - 1) bsum[blockIdx.x] = incl;
}

__global__ __launch_bounds__(256) void scan_add(int* __restrict__ ptr,
                                                const int* __restrict__ boff,
                                                int* __restrict__ cursor, int N, int E) {
    int i = blockIdx.x * 256 + threadIdx.x;
    if (i < N) {
        int v = ptr[i] + boff[i / SCAN_B];
        ptr[i] = v;
        cursor[i] = v;
    }
    if (i == 0) ptr[N] = E;
}

__global__ __launch_bounds__(256) void fill_csr(const int* __restrict__ src,
                                                const int* __restrict__ dst,
                                                int* __restrict__ cursor,
                                                int* __restrict__ sorted, int E) {
    int e = blockIdx.x * 256 + threadIdx.x;
    if (e < E) {
        int p = atomicAdd(&cursor[dst[e]], 1);
        sorted[p] = src[e];
    }
}

// q[n] = Agg(1)[n] = dinv[n]*(sum_nbr dinv[src] + dinv[n])
__global__ __launch_bounds__(256) void qsum_k(const int* __restrict__ ptr,
                                              const int* __restrict__ srcs,
                                              const float* __restrict__ dinv,
                                              float* __restrict__ q, int N) {
    int n = blockIdx.x * 256 + threadIdx.x;
    if (n >= N) return;
    float s = dinv[n];
    int b = ptr[n], e = ptr[n + 1];
    for (int i = b; i < e; i++) s += dinv[srcs[i]];
    q[n] = dinv[n] * s;
}

// actd0 = fp16(x * dinv[n])
__global__ __launch_bounds__(256) void prep_xd(const float* __restrict__ x,
                                               const float* __restrict__ dinv,
                                               ushort* __restrict__ actd, int N16) {
    int p = blockIdx.x * 256 + threadIdx.x;
    if (p >= N16) return;
    int n = p >> 4;
    float d = dinv[n];
    float4 v = reinterpret_cast<const float4*>(x)[p];
    ushort4 o;
    o.x = f2h(v.x * d);
    o.y = f2h(v.y * d);
    o.z = f2h(v.z * d);
    o.w = f2h(v.w * d);
    reinterpret_cast<ushort4*>(actd)[p] = o;
}

// ---------------- per-layer kernels ----------------

// z[n] = dinv[n] * (actd[n] + sum_{src in N(n)} actd[src])   [actd = fp16(act*dinv)]
// optional: BN stats of act = actd*rdinv  (stats of the layer that produced actd)
__global__ __launch_bounds__(256) void agg_gather(const ushort* __restrict__ actd,
                                                  const int* __restrict__ ptr,
                                                  const int* __restrict__ srcs,
                                                  const float* __restrict__ dinv,
                                                  const float* __restrict__ rdinv,
                                                  float* __restrict__ z,
                                                  float* __restrict__ ssum,
                                                  float* __restrict__ sssq, int N) {
    __shared__ float red[2][4][64];
    int lane = threadIdx.x & 63;
    int wv = threadIdx.x >> 6;
    float psum = 0.f, pssq = 0.f;
    for (int n = blockIdx.x * 4 + wv; n < N; n += gridDim.x * 4) {
        int s = __builtin_amdgcn_readfirstlane(ptr[n]);
        int e = __builtin_amdgcn_readfirstlane(ptr[n + 1]);
        float acc = h2f(actd[(size_t)n * 64 + lane]);
        if (ssum) {
            float a = acc * rdinv[n];
            psum += a;
            pssq += a * a;
        }
        int i = s;
        for (; i + 3 < e; i += 4) {
            int u0 = srcs[i], u1 = srcs[i + 1], u2 = srcs[i + 2], u3 = srcs[i + 3];
            float v0 = h2f(actd[(size_t)u0 * 64 + lane]);
            float v1 = h2f(actd[(size_t)u1 * 64 + lane]);
            float v2 = h2f(actd[(size_t)u2 * 64 + lane]);
            float v3 = h2f(actd[(size_t)u3 * 64 + lane]);
            acc += (v0 + v1) + (v2 + v3);
        }
        for (; i < e; i++) acc += h2f(actd[(size_t)srcs[i] * 64 + lane]);
        z[(size_t)n * 64 + lane] = acc * dinv[n];
    }
    if (ssum) {
        red[0][wv][lane] = psum;
        red[1][wv][lane] = pssq;
        __syncthreads();
        if (wv == 0) {
            float t0 = red[0][0][lane] + red[0][1][lane] + red[0][2][lane] + red[0][3][lane];
            float t1 = red[1][0][lane] + red[1][1][lane] + red[1][2][lane] + red[1][3][lane];
            atomicAdd(&ssum[lane], t0);
            atomicAdd(&sssq[lane], t1);
        }
    }
}

// thread t -> node n = t>>2, column-group cg = t&3 (16 outputs each).
// pre[n][j] = sum_k z[n][k]*A[k]*W[k][j] + q[n]*u[j] + b[j]; act = MODE(pre)
// OUT_HALF: write fp16(act*dinv) for the next gather; else raw f32 act.
template <int MODE, bool HAS_AFF, bool OUT_HALF>
__global__ __launch_bounds__(256, 2) void gemm_k(const float* __restrict__ z,
                                                 const float* __restrict__ W,
                                                 const float* __restrict__ Aaf,
                                                 const float* __restrict__ u,
                                                 const float* __restrict__ bias,
                                                 const float* __restrict__ q,
                                                 const float* __restrict__ dinv,
                                                 ushort* __restrict__ outh,
                                                 float* __restrict__ outf, int N) {
    int t = blockIdx.x * 256 + threadIdx.x;
    int n = t >> 2;
    if (n >= N) return;
    int cg = t & 3;
    const float* Wc = W + cg * 16;
    float acc[16];
    float qn = HAS_AFF ? q[n] : 0.0f;
#pragma unroll
    for (int j = 0; j < 16; j++) {
        float b = bias[cg * 16 + j];
        if (HAS_AFF) b = fmaf(qn, u[cg * 16 + j], b);
        acc[j] = b;
    }
    const float4* z4 = reinterpret_cast<const float4*>(z) + (size_t)n * 16;
#pragma unroll
    for (int c4 = 0; c4 < 4; c4++) {
        float zr[16];
#pragma unroll
        for (int i = 0; i < 4; i++) {
            float4 v = z4[c4 * 4 + i];
            zr[4 * i + 0] = v.x;
            zr[4 * i + 1] = v.y;
            zr[4 * i + 2] = v.z;
            zr[4 * i + 3] = v.w;
        }
        if (HAS_AFF) {
#pragma unroll
            for (int i = 0; i < 16; i++) zr[i] *= Aaf[c4 * 16 + i];
        }
#pragma unroll
        for (int kk = 0; kk < 16; kk++) {
            float r = zr[kk];
            const float* wrow = Wc + (size_t)(c4 * 16 + kk) * 64;
#pragma unroll
            for (int j = 0; j < 16; j++) acc[j] = fmaf(r, wrow[j], acc[j]);
        }
    }
#pragma unroll
    for (int j = 0; j < 16; j++) {
        float o = acc[j];
        acc[j] = (MODE == 0) ? sigmoidf_(o) : (MODE == 1 ? o : sigmoidf_(0.5f * o));
    }
    if (OUT_HALF) {
        float dn = dinv[n];
        uint p[8];
#pragma unroll
        for (int jj = 0; jj < 8; jj++) {
            ushort lo = f2h(acc[2 * jj] * dn);
            ushort hi = f2h(acc[2 * jj + 1] * dn);
            p[jj] = (uint)lo | ((uint)hi << 16);
        }
        uint4* ob = reinterpret_cast<uint4*>(outh + (size_t)n * 64 + cg * 16);
        ob[0] = make_uint4(p[0], p[1], p[2], p[3]);
        ob[1] = make_uint4(p[4], p[5], p[6], p[7]);
    } else {
        float4* of = reinterpret_cast<float4*>(outf + (size_t)n * 64 + cg * 16);
        of[0] = make_float4(acc[0], acc[1], acc[2], acc[3]);
        of[1] = make_float4(acc[4], acc[5], acc[6], acc[7]);
        of[2] = make_float4(acc[8], acc[9], acc[10], acc[11]);
        of[3] = make_float4(acc[12], acc[13], acc[14], acc[15]);
    }
}

__global__ __launch_bounds__(256) void stats_f32(const float* __restrict__ act,
                                                 float* __restrict__ ssum,
                                                 float* __restrict__ sssq, int N) {
    __shared__ float red[2][4][64];
    int lane = threadIdx.x & 63;
    int wv = threadIdx.x >> 6;
    float ps = 0.f, pq = 0.f;
    for (int n = blockIdx.x * 4 + wv; n < N; n += gridDim.x * 4) {
        float a = act[(size_t)n * 64 + lane];
        ps += a;
        pq += a * a;
    }
    red[0][wv][lane] = ps;
    red[1][wv][lane] = pq;
    __syncthreads();
    if (wv == 0) {
        float t0 = red[0][0][lane] + red[0][1][lane] + red[0][2][lane] + red[0][3][lane];
        float t1 = red[1][0][lane] + red[1][1][lane] + red[1][2][lane] + red[1][3][lane];
        atomicAdd(&ssum[lane], t0);
        atomicAdd(&sssq[lane], t1);
    }
}

// A[c] = rsqrt(var+eps)*gamma[c];  C[c] = beta[c] - mean*A[c]
__global__ __launch_bounds__(64) void finalize_aff(const float* __restrict__ ssum,
                                                   const float* __restrict__ sssq,
                                                   const float* __restrict__ gamma,
                                                   const float* __restrict__ beta,
                                                   float* __restrict__ A,
                                                   float* __restrict__ C, float invN) {
    int c = threadIdx.x;
    float m = ssum[c] * invN;
    float var = sssq[c] * invN - m * m;
    float rs = rsqrtf(var + 1e-4f);
    float a = rs * gamma[c];
    A[c] = a;
    C[c] = fmaf(-m, a, beta[c]);
}

// u[j] = sum_k C[k]*W[k][j]
__global__ __launch_bounds__(64) void compute_u(const float* __restrict__ C,
                                                const float* __restrict__ W,
                                                float* __restrict__ u) {
    int j = threadIdx.x;
    float s = 0.f;
    for (int k = 0; k < 64; k++) s = fmaf(C[k], W[k * 64 + j], s);
    u[j] = s;
}

__global__ __launch_bounds__(256) void bn_apply_h(const ushort* __restrict__ actd,
                                                  const float* __restrict__ rdinv,
                                                  const float* __restrict__ A,
                                                  const float* __restrict__ C,
                                                  float* __restrict__ out, int N16) {
    int p = blockIdx.x * 256 + threadIdx.x;
    if (p >= N16) return;
    int n = p >> 4;
    int cb = (p & 15) * 4;
    float r = rdinv[n];
    ushort4 v = reinterpret_cast<const ushort4*>(actd)[p];
    float4 o;
    o.x = fmaf(h2f(v.x) * r, A[cb + 0], C[cb + 0]);
    o.y = fmaf(h2f(v.y) * r, A[cb + 1], C[cb + 1]);
    o.z = fmaf(h2f(v.z) * r, A[cb + 2], C[cb + 2]);
    o.w = fmaf(h2f(v.w) * r, A[cb + 3], C[cb + 3]);
    reinterpret_cast<float4*>(out)[p] = o;
}

__global__ __launch_bounds__(256) void bn_apply_f32(const float* __restrict__ act,
                                                    const float* __restrict__ A,
                                                    const float* __restrict__ C,
                                                    float* __restrict__ out, int N16) {
    int p = blockIdx.x * 256 + threadIdx.x;
    if (p >= N16) return;
    int cb = (p & 15) * 4;
    float4 v = reinterpret_cast<const float4*>(act)[p];
    float4 o;
    o.x = fmaf(v.x, A[cb + 0], C[cb + 0]);
    o.y = fmaf(v.y, A[cb + 1], C[cb + 1]);
    o.z = fmaf(v.z, A[cb + 2], C[cb + 2]);
    o.w = fmaf(v.w, A[cb + 3], C[cb + 3]);
    reinterpret_cast<float4*>(out)[p] = o;
}

// ---------------- launch ----------------

extern "C" void kernel_launch(void* const* d_in, const int* in_sizes, int n_in,
                              void* d_out, int out_size, void* d_ws, size_t ws_size,
                              hipStream_t stream) {
    const int N = in_sizes[0] / D;
    const int E = in_sizes[1] / 2;

    const float* x = (const float*)d_in[0];
    const int* ei = (const int*)d_in[1];
    const int* src_in = ei;
    const int* dst_in = ei + E;
    const float* encW = (const float*)d_in[3];
    const float* encb = (const float*)d_in[4];
    const float* encg = (const float*)d_in[5];
    const float* encbe = (const float*)d_in[6];
    const float* attW = (const float*)d_in[7];
    const float* attb = (const float*)d_in[8];
    const float* attg = (const float*)d_in[9];
    const float* attbe = (const float*)d_in[10];
    const float* strW = (const float*)d_in[11];
    const float* strb = (const float*)d_in[12];
    const float* strg = (const float*)d_in[13];
    const float* strbe = (const float*)d_in[14];

    char* ws = (char*)d_ws;
    size_t off = 0;
    auto alloc = [&](size_t bytes) -> char* {
        char* p = ws + off;
        off += (bytes + 255) & ~(size_t)255;
        return p;
    };
    int* cnt = (int*)alloc((size_t)N * 4);
    int* csr = (int*)alloc((size_t)(N + 1) * 4);
    int* cursor = (int*)alloc((size_t)N * 4);
    int* sorted = (int*)alloc((size_t)E * 4);
    int* bsum = (int*)alloc(1024 * 4);
    int* boff = (int*)alloc(1024 * 4);
    int* dummy = (int*)alloc(1024 * 4);
    float* dinv = (float*)alloc((size_t)N * 4);
    float* rdinv = (float*)alloc((size_t)N * 4);
    float* q = (float*)alloc((size_t)N * 4);
    float* stats = (float*)alloc(6 * 128 * 4);
    float* aff = (float*)alloc(6 * 128 * 4);
    float* ubuf = (float*)alloc(6 * 64 * 4);
    float* z = (float*)alloc((size_t)N * D * 4);
    float* fbuf = (float*)alloc((size_t)N * D * 4);
    ushort* hA = (ushort*)alloc((size_t)N * D * 2);
    ushort* hB = (ushort*)alloc((size_t)N * D * 2);

    float* out_str = (float*)d_out;
    float* out_att = out_str + (size_t)N * D;
    float* out_enc = out_att + (size_t)N * D;

    hipMemsetAsync(cnt, 0, (size_t)N * 4, stream);
    hipMemsetAsync(stats, 0, 6 * 128 * 4, stream);

    int gE = (E + 255) / 256;
    int gN = (N + 255) / 256;
    int gN4 = (N * 4 + 255) / 256;
    int nsb = (N + SCAN_B - 1) / SCAN_B;
    int N16 = N * 16;
    int g16 = (N16 + 255) / 256;
    float invN = 1.0f / (float)N;

    // ---- CSR build + norm precompute ----
    count_deg<<<gE, 256, 0, stream>>>(dst_in, cnt, E);
    calc_dinv<<<gN, 256, 0, stream>>>(cnt, dinv, rdinv, N);
    scan_block<<<nsb, SCAN_B, 0, stream>>>(cnt, csr, bsum, N);
    scan_block<<<1, SCAN_B, 0, stream>>>(bsum, boff, dummy, nsb);
    scan_add<<<gN, 256, 0, stream>>>(csr, boff, cursor, N, E);
    fill_csr<<<gE, 256, 0, stream>>>(src_in, dst_in, cursor, sorted, E);
    qsum_k<<<gN, 256, 0, stream>>>(csr, sorted, dinv, q, N);

    float* A0 = aff + 0 * 128; float* C0 = A0 + 64;
    float* A1 = aff + 1 * 128; float* C1 = A1 + 64;
    float* A2 = aff + 2 * 128; float* C2 = A2 + 64;
    float* A3 = aff + 3 * 128; float* C3 = A3 + 64;
    float* A4 = aff + 4 * 128; float* C4 = A4 + 64;
    float* A5 = aff + 5 * 128; float* C5 = A5 + 64;

    // ---- encoder layer 1 ----
    prep_xd<<<g16, 256, 0, stream>>>(x, dinv, hA, N16);
    agg_gather<<<2048, 256, 0, stream>>>(hA, csr, sorted, dinv, rdinv, z,
                                         nullptr, nullptr, N);
    gemm_k<0, false, true><<<gN4, 256, 0, stream>>>(z, encW, nullptr, nullptr,
                                                    encb, q, dinv, hB, nullptr, N);
    // ---- encoder layer 2 ----
    agg_gather<<<2048, 256, 0, stream>>>(hB, csr, sorted, dinv, rdinv, z,
                                         stats + 0, stats + 64, N);
    finalize_aff<<<1, 64, 0, stream>>>(stats + 0, stats + 64, encg, encbe, A0, C0, invN);
    compute_u<<<1, 64, 0, stream>>>(C0, encW + 4096, ubuf + 0);
    gemm_k<0, true, true><<<gN4, 256, 0, stream>>>(z, encW + 4096, A0, ubuf + 0,
                                                   encb + 64, q, dinv, hA, nullptr, N);
    // ---- z2 = Agg(x_enc-act), shared by att1 & str1; also enc2 stats ----
    agg_gather<<<2048, 256, 0, stream>>>(hA, csr, sorted, dinv, rdinv, z,
                                         stats + 128, stats + 192, N);
    finalize_aff<<<1, 64, 0, stream>>>(stats + 128, stats + 192, encg + 64,
                                       encbe + 64, A1, C1, invN);
    compute_u<<<1, 64, 0, stream>>>(C1, attW, ubuf + 64);
    compute_u<<<1, 64, 0, stream>>>(C1, strW, ubuf + 128);
    bn_apply_h<<<g16, 256, 0, stream>>>(hA, rdinv, A1, C1, out_enc, N16);
    gemm_k<0, true, true><<<gN4, 256, 0, stream>>>(z, attW, A1, ubuf + 64, attb,
                                                   q, dinv, hB, nullptr, N);
    gemm_k<0, true, true><<<gN4, 256, 0, stream>>>(z, strW, A1, ubuf + 128, strb,
                                                   q, dinv, hA, nullptr, N);
    // ---- attribute layer 2 (terminal, linear) ----
    agg_gather<<<2048, 256, 0, stream>>>(hB, csr, sorted, dinv, rdinv, z,
                                         stats + 256, stats + 320, N);
    finalize_aff<<<1, 64, 0, stream>>>(stats + 256, stats + 320, attg, attbe,
                                       A2, C2, invN);
    compute_u<<<1, 64, 0, stream>>>(C2, attW + 4096, ubuf + 192);
    gemm_k<1, true, false><<<gN4, 256, 0, stream>>>(z, attW + 4096, A2, ubuf + 192,
                                                    attb + 64, q, dinv, nullptr,
                                                    fbuf, N);
    stats_f32<<<2048, 256, 0, stream>>>(fbuf, stats + 384, stats + 448, N);
    finalize_aff<<<1, 64, 0, stream>>>(stats + 384, stats + 448, attg + 64,
                                       attbe + 64, A3, C3, invN);
    bn_apply_f32<<<g16, 256, 0, stream>>>(fbuf, A3, C3, out_att, N16);
    // ---- structure layer 2 (terminal, sigmoid(0.5x)) ----
    agg_gather<<<2048, 256, 0, stream>>>(hA, csr, sorted, dinv, rdinv, z,
                                         stats + 512, stats + 576, N);
    finalize_aff<<<1, 64, 0, stream>>>(stats + 512, stats + 576, strg, strbe,
                                       A4, C4, invN);
    compute_u<<<1, 64, 0, stream>>>(C4, strW + 4096, ubuf + 320);
    gemm_k<2, true, false><<<gN4, 256, 0, stream>>>(z, strW + 4096, A4, ubuf + 320,
                                                    strb + 64, q, dinv, nullptr,
                                                    fbuf, N);
    stats_f32<<<2048, 256, 0, stream>>>(fbuf, stats + 640, stats + 704, N);
    finalize_aff<<<1, 64, 0, stream>>>(stats + 640, stats + 704, strg + 64,
                                       strbe + 64, A5, C5, invN);
    bn_apply_f32<<<g16, 256, 0, stream>>>(fbuf, A5, C5, out_str, N16);
}